// Round 1
// baseline (1320.739 us; speedup 1.0000x reference)
//
#include <hip/hip_runtime.h>
#include <hip/hip_bf16.h>

// Problem constants
#define NN 50000
#define EE 800000
#define DD 128
#define FF 16
#define LL 5
#define NPART 3125   // row-tile blocks in GEMMs (50000/16)

typedef __attribute__((ext_vector_type(8))) short bf16x8;
typedef __attribute__((ext_vector_type(4))) float f32x4;

__device__ __forceinline__ unsigned short f2bf(float f) {
    union { float f; unsigned int u; } v; v.f = f;
    unsigned int u = v.u;
    unsigned int r = (u + 0x7fffu + ((u >> 16) & 1u)) >> 16;
    return (unsigned short)r;
}
__device__ __forceinline__ float bf2f(unsigned short s) {
    union { unsigned int u; float f; } v; v.u = ((unsigned int)s) << 16;
    return v.f;
}

// ---------------- node encoder: h = x @ W_node + b_node ----------------
__global__ void k_node_enc(const float* __restrict__ x, const float* __restrict__ Wn,
                           const float* __restrict__ bn, float* __restrict__ h)
{
    const int t = blockIdx.x * 256 + threadIdx.x;   // grid exactly N*128
    const int i = t >> 7, d = t & 127;
    const float4* x4 = (const float4*)(x + (size_t)i * 16);
    float4 a0 = x4[0], a1 = x4[1], a2 = x4[2], a3 = x4[3];
    float acc = bn[d];
    acc += a0.x*Wn[0*128+d] + a0.y*Wn[1*128+d] + a0.z*Wn[2*128+d] + a0.w*Wn[3*128+d];
    acc += a1.x*Wn[4*128+d] + a1.y*Wn[5*128+d] + a1.z*Wn[6*128+d] + a1.w*Wn[7*128+d];
    acc += a2.x*Wn[8*128+d] + a2.y*Wn[9*128+d] + a2.z*Wn[10*128+d] + a2.w*Wn[11*128+d];
    acc += a3.x*Wn[12*128+d] + a3.y*Wn[13*128+d] + a3.z*Wn[14*128+d] + a3.w*Wn[15*128+d];
    h[t] = acc;
}

// ---------------- CSR build ----------------
__global__ void k_count(const int* __restrict__ ei, int* __restrict__ counts)
{
    const int e = blockIdx.x * 256 + threadIdx.x;   // grid exactly E
    atomicAdd(&counts[ei[EE + e]], 1);
}

__global__ __launch_bounds__(1024) void k_scan(int* __restrict__ counts, int* __restrict__ row_ptr)
{
    __shared__ int sh[1024];
    __shared__ int carry;
    const int tid = threadIdx.x;
    if (tid == 0) carry = 0;
    __syncthreads();
    for (int base = 0; base < NN; base += 1024) {
        const int i = base + tid;
        int v = (i < NN) ? counts[i] : 0;
        sh[tid] = v;
        __syncthreads();
        for (int off = 1; off < 1024; off <<= 1) {
            int add = (tid >= off) ? sh[tid - off] : 0;
            __syncthreads();
            sh[tid] += add;
            __syncthreads();
        }
        const int incl = sh[tid];
        const int base_out = carry;
        if (i < NN) {
            const int ex = base_out + incl - v;
            row_ptr[i] = ex;
            counts[i]  = ex;   // becomes fill cursor
        }
        __syncthreads();
        if (tid == 1023) carry = base_out + incl;
        __syncthreads();
    }
    if (tid == 0) row_ptr[NN] = carry;
}

__global__ void k_fill(const int* __restrict__ ei, int* __restrict__ cursor, int2* __restrict__ eidsrc)
{
    const int e = blockIdx.x * 256 + threadIdx.x;   // grid exactly E
    const int d = ei[EE + e];
    const int p = atomicAdd(&cursor[d], 1);
    eidsrc[p] = make_int2(e, ei[e]);
}

// ---------------- weight repack to MFMA B-fragment layout ----------------
// B-frag (16x16x32 bf16): lane holds B[k0 + (lane>>4)*8 + j][n0 + (lane&15)], j=0..7
__global__ void k_pack(const float* __restrict__ W1, const float* __restrict__ W2,
                       unsigned short* __restrict__ Wp1, unsigned short* __restrict__ Wp2)
{
    int t = blockIdx.x * 256 + threadIdx.x;   // grid exactly 2*L*32768
    const int total = LL * 32768;
    if (t < total) {
        const int l = t >> 15, r = t & 32767;
        const int j = r & 7, lane = (r >> 3) & 63, kt = (r >> 9) & 3, nt = r >> 11;
        const int k = kt * 32 + (lane >> 4) * 8 + j;
        const int n = nt * 16 + (lane & 15);
        Wp1[t] = f2bf(W1[(size_t)l * 32768 + k * 256 + n]);
    } else {
        t -= total;
        const int l = t >> 15, r = t & 32767;
        const int j = r & 7, lane = (r >> 3) & 63, kt = (r >> 9) & 7, nt = r >> 12;
        const int k = kt * 32 + (lane >> 4) * 8 + j;
        const int n = nt * 16 + (lane & 15);
        Wp2[t] = f2bf(W2[(size_t)l * 32768 + k * 128 + n]);
    }
}

// ---------------- fused edge-encode + gather + CSR aggregate ----------------
__global__ __launch_bounds__(128) void k_agg(
    const float* __restrict__ h, const float* __restrict__ ea,
    const float* __restrict__ We_l, const float* __restrict__ be_l,
    const int* __restrict__ row_ptr, const int2* __restrict__ eidsrc,
    float* __restrict__ agg)
{
    const int v = blockIdx.x;
    const int d = threadIdx.x;
    float w[16];
    #pragma unroll
    for (int f = 0; f < 16; ++f) w[f] = We_l[f * 128 + d];
    const float bed = be_l[d];
    float acc = 0.f;
    const int kbeg = row_ptr[v], kend = row_ptr[v + 1];
    for (int k = kbeg; k < kend; ++k) {
        const int2 es = eidsrc[k];
        const float4* e4 = (const float4*)(ea + (size_t)es.x * 16);
        const float4 a0 = e4[0], a1 = e4[1], a2 = e4[2], a3 = e4[3];
        const float hs = h[(size_t)es.y * 128 + d];
        float e = bed;
        e += a0.x*w[0]  + a0.y*w[1]  + a0.z*w[2]  + a0.w*w[3];
        e += a1.x*w[4]  + a1.y*w[5]  + a1.z*w[6]  + a1.w*w[7];
        e += a2.x*w[8]  + a2.y*w[9]  + a2.z*w[10] + a2.w*w[11];
        e += a3.x*w[12] + a3.y*w[13] + a3.z*w[14] + a3.w*w[15];
        const float msg = hs + e;
        acc += msg > 0.f ? msg : 0.f;
    }
    agg[(size_t)v * 128 + d] = acc;
}

// ---------------- GEMM1: t = ((1+eps)h + agg) @ W1, + BN1 partial stats ----------------
__global__ __launch_bounds__(256) void k_gemmB(
    const float* __restrict__ h, const float* __restrict__ agg,
    const float* __restrict__ eps_gin, const int l,
    const unsigned short* __restrict__ Wp,
    unsigned short* __restrict__ t_bf,
    float* __restrict__ ps, float* __restrict__ pq)
{
    __shared__ __align__(16) unsigned short zs[16 * 136];
    const int tid = threadIdx.x;
    const int r0 = blockIdx.x * 16;
    const float epsv = 1.0f + eps_gin[l];
    {
        const int row = tid & 15, c0 = (tid >> 4) * 8;
        const float4* hp = (const float4*)(h   + (size_t)(r0 + row) * 128 + c0);
        const float4* ap = (const float4*)(agg + (size_t)(r0 + row) * 128 + c0);
        const float4 h0 = hp[0], h1 = hp[1], a0 = ap[0], a1 = ap[1];
        union { bf16x8 v; unsigned short u[8]; } pk;
        pk.u[0] = f2bf(epsv*h0.x + a0.x);
        pk.u[1] = f2bf(epsv*h0.y + a0.y);
        pk.u[2] = f2bf(epsv*h0.z + a0.z);
        pk.u[3] = f2bf(epsv*h0.w + a0.w);
        pk.u[4] = f2bf(epsv*h1.x + a1.x);
        pk.u[5] = f2bf(epsv*h1.y + a1.y);
        pk.u[6] = f2bf(epsv*h1.z + a1.z);
        pk.u[7] = f2bf(epsv*h1.w + a1.w);
        *(bf16x8*)(&zs[row * 136 + c0]) = pk.v;
    }
    __syncthreads();
    const int w = tid >> 6, l6 = tid & 63, m = l6 & 15, quad = l6 >> 4;
    const f32x4 z4 = {0.f, 0.f, 0.f, 0.f};
    f32x4 acc[4] = {z4, z4, z4, z4};
    const bf16x8* Wv = (const bf16x8*)Wp;
    #pragma unroll
    for (int kt = 0; kt < 4; ++kt) {
        const bf16x8 a = *(const bf16x8*)(&zs[m * 136 + kt * 32 + quad * 8]);
        #pragma unroll
        for (int f = 0; f < 4; ++f) {
            const bf16x8 b = Wv[((w * 4 + f) * 4 + kt) * 64 + l6];
            acc[f] = __builtin_amdgcn_mfma_f32_16x16x32_bf16(a, b, acc[f], 0, 0, 0);
        }
    }
    const int rowb = r0 + quad * 4;
    #pragma unroll
    for (int f = 0; f < 4; ++f) {
        const int col = w * 64 + f * 16 + m;
        float ssum = 0.f, ssq = 0.f;
        #pragma unroll
        for (int r = 0; r < 4; ++r) {
            const float val = acc[f][r];
            t_bf[(size_t)(rowb + r) * 256 + col] = f2bf(val);
            ssum += val; ssq += val * val;
        }
        ssum += __shfl_xor(ssum, 16); ssum += __shfl_xor(ssum, 32);
        ssq  += __shfl_xor(ssq , 16); ssq  += __shfl_xor(ssq , 32);
        if (quad == 0) {
            ps[(size_t)col * NPART + blockIdx.x] = ssum;
            pq[(size_t)col * NPART + blockIdx.x] = ssq;
        }
    }
}

// ---------------- BN stat fold: per-channel scale/shift ----------------
__global__ void k_bnstat(const float* __restrict__ ps, const float* __restrict__ pq,
                         const float* __restrict__ g, const float* __restrict__ beta,
                         float* __restrict__ sc, float* __restrict__ sh)
{
    const int c = blockIdx.x;
    const int tid = threadIdx.x;   // 256 threads
    const float* pr = ps + (size_t)c * NPART;
    const float* qr = pq + (size_t)c * NPART;
    float s = 0.f, q = 0.f;
    for (int i = tid; i < NPART; i += 256) { s += pr[i]; q += qr[i]; }
    #pragma unroll
    for (int off = 1; off < 64; off <<= 1) { s += __shfl_xor(s, off); q += __shfl_xor(q, off); }
    __shared__ float ls[4], lq[4];
    const int wv = tid >> 6;
    if ((tid & 63) == 0) { ls[wv] = s; lq[wv] = q; }
    __syncthreads();
    if (tid == 0) {
        const float S = ls[0] + ls[1] + ls[2] + ls[3];
        const float Q = lq[0] + lq[1] + lq[2] + lq[3];
        const float mean = S * (1.0f / NN);
        const float var  = Q * (1.0f / NN) - mean * mean;
        const float rs = rsqrtf(var + 1e-5f);
        const float scale = g[c] * rs;
        sc[c] = scale;
        sh[c] = beta[c] - mean * scale;
    }
}

// ---------------- GEMM2: v = relu(BN1(t)) @ W2, + BN2 partial stats ----------------
__global__ __launch_bounds__(128) void k_gemmD(
    const unsigned short* __restrict__ t_bf,
    const float* __restrict__ sc1, const float* __restrict__ sh1,
    const unsigned short* __restrict__ Wp,
    float* __restrict__ vbuf,
    float* __restrict__ ps, float* __restrict__ pq)
{
    __shared__ __align__(16) unsigned short us[16 * 264];
    const int tid = threadIdx.x;
    const int r0 = blockIdx.x * 16;
    {
        const int row = tid & 15, g8 = (tid >> 4) * 8;
        #pragma unroll
        for (int cc = 0; cc < 4; ++cc) {
            const int c = cc * 64 + g8;
            union { bf16x8 v; unsigned short u[8]; } in, o;
            in.v = *(const bf16x8*)(t_bf + (size_t)(r0 + row) * 256 + c);
            const float4* scp = (const float4*)(sc1 + c);
            const float4* shp = (const float4*)(sh1 + c);
            const float4 s0 = scp[0], s1 = scp[1], b0 = shp[0], b1 = shp[1];
            float xv;
            xv = bf2f(in.u[0])*s0.x + b0.x; o.u[0] = f2bf(xv > 0.f ? xv : 0.f);
            xv = bf2f(in.u[1])*s0.y + b0.y; o.u[1] = f2bf(xv > 0.f ? xv : 0.f);
            xv = bf2f(in.u[2])*s0.z + b0.z; o.u[2] = f2bf(xv > 0.f ? xv : 0.f);
            xv = bf2f(in.u[3])*s0.w + b0.w; o.u[3] = f2bf(xv > 0.f ? xv : 0.f);
            xv = bf2f(in.u[4])*s1.x + b1.x; o.u[4] = f2bf(xv > 0.f ? xv : 0.f);
            xv = bf2f(in.u[5])*s1.y + b1.y; o.u[5] = f2bf(xv > 0.f ? xv : 0.f);
            xv = bf2f(in.u[6])*s1.z + b1.z; o.u[6] = f2bf(xv > 0.f ? xv : 0.f);
            xv = bf2f(in.u[7])*s1.w + b1.w; o.u[7] = f2bf(xv > 0.f ? xv : 0.f);
            *(bf16x8*)(&us[row * 264 + c]) = o.v;
        }
    }
    __syncthreads();
    const int w = tid >> 6, l6 = tid & 63, m = l6 & 15, quad = l6 >> 4;
    const f32x4 z4 = {0.f, 0.f, 0.f, 0.f};
    f32x4 acc[4] = {z4, z4, z4, z4};
    const bf16x8* Wv = (const bf16x8*)Wp;
    #pragma unroll
    for (int kt = 0; kt < 8; ++kt) {
        const bf16x8 a = *(const bf16x8*)(&us[m * 264 + kt * 32 + quad * 8]);
        #pragma unroll
        for (int f = 0; f < 4; ++f) {
            const bf16x8 b = Wv[((w * 4 + f) * 8 + kt) * 64 + l6];
            acc[f] = __builtin_amdgcn_mfma_f32_16x16x32_bf16(a, b, acc[f], 0, 0, 0);
        }
    }
    const int rowb = r0 + quad * 4;
    #pragma unroll
    for (int f = 0; f < 4; ++f) {
        const int col = w * 64 + f * 16 + m;
        float ssum = 0.f, ssq = 0.f;
        #pragma unroll
        for (int r = 0; r < 4; ++r) {
            const float val = acc[f][r];
            vbuf[(size_t)(rowb + r) * 128 + col] = val;
            ssum += val; ssq += val * val;
        }
        ssum += __shfl_xor(ssum, 16); ssum += __shfl_xor(ssum, 32);
        ssq  += __shfl_xor(ssq , 16); ssq  += __shfl_xor(ssq , 32);
        if (quad == 0) {
            ps[(size_t)col * NPART + blockIdx.x] = ssum;
            pq[(size_t)col * NPART + blockIdx.x] = ssq;
        }
    }
}

// ---------------- BN2 + optional relu + residual ----------------
__global__ void k_fin(const float* __restrict__ vbuf, const float* __restrict__ sc2,
                      const float* __restrict__ sh2, float* __restrict__ h, const int do_relu)
{
    const int t = blockIdx.x * 256 + threadIdx.x;   // grid exactly N*128
    const int c = t & 127;
    float z = vbuf[t] * sc2[c] + sh2[c];
    if (do_relu) z = z > 0.f ? z : 0.f;
    h[t] += z;
}

extern "C" void kernel_launch(void* const* d_in, const int* in_sizes, int n_in,
                              void* d_out, int out_size, void* d_ws, size_t ws_size,
                              hipStream_t stream)
{
    const float* x       = (const float*)d_in[0];
    const int*   ei      = (const int*)  d_in[1];
    const float* ea      = (const float*)d_in[2];
    const float* W_node  = (const float*)d_in[3];
    const float* b_node  = (const float*)d_in[4];
    const float* We      = (const float*)d_in[5];
    const float* be      = (const float*)d_in[6];
    const float* eps_gin = (const float*)d_in[7];
    const float* W1      = (const float*)d_in[8];
    // d_in[9] = b1: cancels exactly under BN1 (mean subtraction)
    const float* g1      = (const float*)d_in[10];
    const float* beta1   = (const float*)d_in[11];
    const float* W2      = (const float*)d_in[12];
    // d_in[13] = b2: cancels exactly under BN2
    const float* g_bn    = (const float*)d_in[14];
    const float* beta_bn = (const float*)d_in[15];

    float* h = (float*)d_out;

    char* W = (char*)d_ws;
    int*   counts  = (int*)  (W + 0);            // 200000 B (also fill cursor)
    int*   row_ptr = (int*)  (W + 200000);       // 200016 B
    float* sc1     = (float*)(W + 400016);       // 1024 B
    float* sh1     = (float*)(W + 401040);       // 1024 B
    float* sc2     = (float*)(W + 402064);       // 512 B
    float* sh2     = (float*)(W + 402576);       // 512 B
    float* ps1     = (float*)(W + 403088);       // 256*3125*4 = 3200000 B
    float* pq1     = (float*)(W + 3603088);      // 3200000 B
    float* ps2     = (float*)(W + 6803088);      // 128*3125*4 = 1600000 B
    float* pq2     = (float*)(W + 8403088);      // 1600000 B
    int2*  eidsrc  = (int2*) (W + 10003088);     // 6400000 B
    unsigned short* Wp1 = (unsigned short*)(W + 16403088);  // 327680 B
    unsigned short* Wp2 = (unsigned short*)(W + 16730768);  // 327680 B
    float* agg     = (float*)(W + 17058448);     // 25600000 B
    unsigned short* t_bf = (unsigned short*)(W + 42658448); // 25600000 B
    float* vbuf    = (float*)(W + 68258448);     // 25600000 B -> total ~93.9 MB

    (void)hipMemsetAsync(counts, 0, 200000, stream);

    k_node_enc<<<dim3(NN * DD / 256), dim3(256), 0, stream>>>(x, W_node, b_node, h);
    k_count<<<dim3(EE / 256), dim3(256), 0, stream>>>(ei, counts);
    k_scan<<<dim3(1), dim3(1024), 0, stream>>>(counts, row_ptr);
    k_fill<<<dim3(EE / 256), dim3(256), 0, stream>>>(ei, counts, eidsrc);
    k_pack<<<dim3(2 * LL * 32768 / 256), dim3(256), 0, stream>>>(W1, W2, Wp1, Wp2);

    for (int l = 0; l < LL; ++l) {
        k_agg<<<dim3(NN), dim3(128), 0, stream>>>(
            h, ea, We + (size_t)l * FF * DD, be + (size_t)l * DD, row_ptr, eidsrc, agg);
        k_gemmB<<<dim3(NPART), dim3(256), 0, stream>>>(
            h, agg, eps_gin, l, Wp1 + (size_t)l * 32768, t_bf, ps1, pq1);
        k_bnstat<<<dim3(256), dim3(256), 0, stream>>>(
            ps1, pq1, g1 + (size_t)l * 256, beta1 + (size_t)l * 256, sc1, sh1);
        k_gemmD<<<dim3(NPART), dim3(128), 0, stream>>>(
            t_bf, sc1, sh1, Wp2 + (size_t)l * 32768, vbuf, ps2, pq2);
        k_bnstat<<<dim3(128), dim3(256), 0, stream>>>(
            ps2, pq2, g_bn + (size_t)l * 128, beta_bn + (size_t)l * 128, sc2, sh2);
        k_fin<<<dim3(NN * DD / 256), dim3(256), 0, stream>>>(vbuf, sc2, sh2, h, (l < LL - 1) ? 1 : 0);
    }
}

// Round 2
// 1217.118 us; speedup vs baseline: 1.0851x; 1.0851x over previous
//
#include <hip/hip_runtime.h>
#include <hip/hip_bf16.h>

// Problem constants
#define NN 50000
#define EE 800000
#define DD 128
#define FF 16
#define LL 5
#define NPART 3125   // row-tile blocks in GEMMs (50000/16)

typedef __attribute__((ext_vector_type(8))) short bf16x8;
typedef __attribute__((ext_vector_type(4))) float f32x4;

__device__ __forceinline__ unsigned short f2bf(float f) {
    union { float f; unsigned int u; } v; v.f = f;
    unsigned int u = v.u;
    unsigned int r = (u + 0x7fffu + ((u >> 16) & 1u)) >> 16;
    return (unsigned short)r;
}
__device__ __forceinline__ float bf2f(unsigned short s) {
    union { unsigned int u; float f; } v; v.u = ((unsigned int)s) << 16;
    return v.f;
}

// ---------------- node encoder: h = x @ W_node + b_node ----------------
__global__ void k_node_enc(const float* __restrict__ x, const float* __restrict__ Wn,
                           const float* __restrict__ bn, float* __restrict__ h)
{
    const int t = blockIdx.x * 256 + threadIdx.x;   // grid exactly N*128
    const int i = t >> 7, d = t & 127;
    const float4* x4 = (const float4*)(x + (size_t)i * 16);
    float4 a0 = x4[0], a1 = x4[1], a2 = x4[2], a3 = x4[3];
    float acc = bn[d];
    acc += a0.x*Wn[0*128+d] + a0.y*Wn[1*128+d] + a0.z*Wn[2*128+d] + a0.w*Wn[3*128+d];
    acc += a1.x*Wn[4*128+d] + a1.y*Wn[5*128+d] + a1.z*Wn[6*128+d] + a1.w*Wn[7*128+d];
    acc += a2.x*Wn[8*128+d] + a2.y*Wn[9*128+d] + a2.z*Wn[10*128+d] + a2.w*Wn[11*128+d];
    acc += a3.x*Wn[12*128+d] + a3.y*Wn[13*128+d] + a3.z*Wn[14*128+d] + a3.w*Wn[15*128+d];
    h[t] = acc;
}

// ---------------- CSR build ----------------
__global__ void k_count(const int* __restrict__ ei, int* __restrict__ counts)
{
    const int e = blockIdx.x * 256 + threadIdx.x;   // grid exactly E
    atomicAdd(&counts[ei[EE + e]], 1);
}

__global__ __launch_bounds__(1024) void k_scan(int* __restrict__ counts, int* __restrict__ row_ptr)
{
    __shared__ int sh[1024];
    __shared__ int carry;
    const int tid = threadIdx.x;
    if (tid == 0) carry = 0;
    __syncthreads();
    for (int base = 0; base < NN; base += 1024) {
        const int i = base + tid;
        int v = (i < NN) ? counts[i] : 0;
        sh[tid] = v;
        __syncthreads();
        for (int off = 1; off < 1024; off <<= 1) {
            int add = (tid >= off) ? sh[tid - off] : 0;
            __syncthreads();
            sh[tid] += add;
            __syncthreads();
        }
        const int incl = sh[tid];
        const int base_out = carry;
        if (i < NN) {
            const int ex = base_out + incl - v;
            row_ptr[i] = ex;
            counts[i]  = ex;   // becomes fill cursor
        }
        __syncthreads();
        if (tid == 1023) carry = base_out + incl;
        __syncthreads();
    }
    if (tid == 0) row_ptr[NN] = carry;
}

__global__ void k_fill(const int* __restrict__ ei, int* __restrict__ cursor, int2* __restrict__ eidsrc)
{
    const int e = blockIdx.x * 256 + threadIdx.x;   // grid exactly E
    const int d = ei[EE + e];
    const int p = atomicAdd(&cursor[d], 1);
    eidsrc[p] = make_int2(e, ei[e]);
}

// ---------------- weight repack to MFMA B-fragment layout ----------------
// B-frag (16x16x32 bf16): lane holds B[k0 + (lane>>4)*8 + j][n0 + (lane&15)], j=0..7
__global__ void k_pack(const float* __restrict__ W1, const float* __restrict__ W2,
                       unsigned short* __restrict__ Wp1, unsigned short* __restrict__ Wp2)
{
    int t = blockIdx.x * 256 + threadIdx.x;   // grid exactly 2*L*32768
    const int total = LL * 32768;
    if (t < total) {
        const int l = t >> 15, r = t & 32767;
        const int j = r & 7, lane = (r >> 3) & 63, kt = (r >> 9) & 3, nt = r >> 11;
        const int k = kt * 32 + (lane >> 4) * 8 + j;
        const int n = nt * 16 + (lane & 15);
        Wp1[t] = f2bf(W1[(size_t)l * 32768 + k * 256 + n]);
    } else {
        t -= total;
        const int l = t >> 15, r = t & 32767;
        const int j = r & 7, lane = (r >> 3) & 63, kt = (r >> 9) & 7, nt = r >> 12;
        const int k = kt * 32 + (lane >> 4) * 8 + j;
        const int n = nt * 16 + (lane & 15);
        Wp2[t] = f2bf(W2[(size_t)l * 32768 + k * 128 + n]);
    }
}

// ---------------- fused edge-encode + gather + CSR aggregate ----------------
// Latency-bound fix (R1): 4-way edge unroll with independent accumulators so
// 4 gather chains are in flight; readfirstlane forces eidsrc/ea accesses onto
// the scalar path (ea row is wave-uniform -> K$ instead of 128x vector L1).
__global__ __launch_bounds__(128) void k_agg(
    const float* __restrict__ h, const float* __restrict__ ea,
    const float* __restrict__ We_l, const float* __restrict__ be_l,
    const int* __restrict__ row_ptr, const int2* __restrict__ eidsrc,
    float* __restrict__ agg)
{
    const int v = blockIdx.x;
    const int d = threadIdx.x;
    float w[16];
    #pragma unroll
    for (int f = 0; f < 16; ++f) w[f] = We_l[f * 128 + d];
    const float bed = be_l[d];
    const int kbeg = __builtin_amdgcn_readfirstlane(row_ptr[v]);
    const int kend = __builtin_amdgcn_readfirstlane(row_ptr[v + 1]);
    float acc0 = 0.f, acc1 = 0.f, acc2 = 0.f, acc3 = 0.f;
    int k = kbeg;

#define EDGE_DOT(eidx_, hs_, out_) do {                                     \
        const float4* p_ = (const float4*)(ea + (size_t)(eidx_) * 16);      \
        const float4 a0_ = p_[0], a1_ = p_[1], a2_ = p_[2], a3_ = p_[3];    \
        float e_ = bed;                                                     \
        e_ += a0_.x*w[0]  + a0_.y*w[1]  + a0_.z*w[2]  + a0_.w*w[3];         \
        e_ += a1_.x*w[4]  + a1_.y*w[5]  + a1_.z*w[6]  + a1_.w*w[7];         \
        e_ += a2_.x*w[8]  + a2_.y*w[9]  + a2_.z*w[10] + a2_.w*w[11];        \
        e_ += a3_.x*w[12] + a3_.y*w[13] + a3_.z*w[14] + a3_.w*w[15];        \
        const float m_ = (hs_) + e_;                                        \
        (out_) += m_ > 0.f ? m_ : 0.f;                                      \
    } while (0)

    for (; k + 4 <= kend; k += 4) {
        const int2 q0 = eidsrc[k + 0];
        const int2 q1 = eidsrc[k + 1];
        const int2 q2 = eidsrc[k + 2];
        const int2 q3 = eidsrc[k + 3];
        const int e0 = __builtin_amdgcn_readfirstlane(q0.x);
        const int s0 = __builtin_amdgcn_readfirstlane(q0.y);
        const int e1 = __builtin_amdgcn_readfirstlane(q1.x);
        const int s1 = __builtin_amdgcn_readfirstlane(q1.y);
        const int e2 = __builtin_amdgcn_readfirstlane(q2.x);
        const int s2 = __builtin_amdgcn_readfirstlane(q2.y);
        const int e3 = __builtin_amdgcn_readfirstlane(q3.x);
        const int s3 = __builtin_amdgcn_readfirstlane(q3.y);
        const float hs0 = h[(size_t)s0 * 128 + d];
        const float hs1 = h[(size_t)s1 * 128 + d];
        const float hs2 = h[(size_t)s2 * 128 + d];
        const float hs3 = h[(size_t)s3 * 128 + d];
        EDGE_DOT(e0, hs0, acc0);
        EDGE_DOT(e1, hs1, acc1);
        EDGE_DOT(e2, hs2, acc2);
        EDGE_DOT(e3, hs3, acc3);
    }
    for (; k < kend; ++k) {
        const int2 q = eidsrc[k];
        const int e0 = __builtin_amdgcn_readfirstlane(q.x);
        const int s0 = __builtin_amdgcn_readfirstlane(q.y);
        const float hs0 = h[(size_t)s0 * 128 + d];
        EDGE_DOT(e0, hs0, acc0);
    }
#undef EDGE_DOT
    agg[(size_t)v * 128 + d] = (acc0 + acc1) + (acc2 + acc3);
}

// ---------------- GEMM1: t = ((1+eps)h + agg) @ W1, + BN1 partial stats ----------------
__global__ __launch_bounds__(256) void k_gemmB(
    const float* __restrict__ h, const float* __restrict__ agg,
    const float* __restrict__ eps_gin, const int l,
    const unsigned short* __restrict__ Wp,
    unsigned short* __restrict__ t_bf,
    float* __restrict__ ps, float* __restrict__ pq)
{
    __shared__ __align__(16) unsigned short zs[16 * 136];
    const int tid = threadIdx.x;
    const int r0 = blockIdx.x * 16;
    const float epsv = 1.0f + eps_gin[l];
    {
        const int row = tid & 15, c0 = (tid >> 4) * 8;
        const float4* hp = (const float4*)(h   + (size_t)(r0 + row) * 128 + c0);
        const float4* ap = (const float4*)(agg + (size_t)(r0 + row) * 128 + c0);
        const float4 h0 = hp[0], h1 = hp[1], a0 = ap[0], a1 = ap[1];
        union { bf16x8 v; unsigned short u[8]; } pk;
        pk.u[0] = f2bf(epsv*h0.x + a0.x);
        pk.u[1] = f2bf(epsv*h0.y + a0.y);
        pk.u[2] = f2bf(epsv*h0.z + a0.z);
        pk.u[3] = f2bf(epsv*h0.w + a0.w);
        pk.u[4] = f2bf(epsv*h1.x + a1.x);
        pk.u[5] = f2bf(epsv*h1.y + a1.y);
        pk.u[6] = f2bf(epsv*h1.z + a1.z);
        pk.u[7] = f2bf(epsv*h1.w + a1.w);
        *(bf16x8*)(&zs[row * 136 + c0]) = pk.v;
    }
    __syncthreads();
    const int w = tid >> 6, l6 = tid & 63, m = l6 & 15, quad = l6 >> 4;
    const f32x4 z4 = {0.f, 0.f, 0.f, 0.f};
    f32x4 acc[4] = {z4, z4, z4, z4};
    const bf16x8* Wv = (const bf16x8*)Wp;
    #pragma unroll
    for (int kt = 0; kt < 4; ++kt) {
        const bf16x8 a = *(const bf16x8*)(&zs[m * 136 + kt * 32 + quad * 8]);
        #pragma unroll
        for (int f = 0; f < 4; ++f) {
            const bf16x8 b = Wv[((w * 4 + f) * 4 + kt) * 64 + l6];
            acc[f] = __builtin_amdgcn_mfma_f32_16x16x32_bf16(a, b, acc[f], 0, 0, 0);
        }
    }
    const int rowb = r0 + quad * 4;
    #pragma unroll
    for (int f = 0; f < 4; ++f) {
        const int col = w * 64 + f * 16 + m;
        float ssum = 0.f, ssq = 0.f;
        #pragma unroll
        for (int r = 0; r < 4; ++r) {
            const float val = acc[f][r];
            t_bf[(size_t)(rowb + r) * 256 + col] = f2bf(val);
            ssum += val; ssq += val * val;
        }
        ssum += __shfl_xor(ssum, 16); ssum += __shfl_xor(ssum, 32);
        ssq  += __shfl_xor(ssq , 16); ssq  += __shfl_xor(ssq , 32);
        if (quad == 0) {
            ps[(size_t)col * NPART + blockIdx.x] = ssum;
            pq[(size_t)col * NPART + blockIdx.x] = ssq;
        }
    }
}

// ---------------- BN stat fold: per-channel scale/shift ----------------
__global__ void k_bnstat(const float* __restrict__ ps, const float* __restrict__ pq,
                         const float* __restrict__ g, const float* __restrict__ beta,
                         float* __restrict__ sc, float* __restrict__ sh)
{
    const int c = blockIdx.x;
    const int tid = threadIdx.x;   // 256 threads
    const float* pr = ps + (size_t)c * NPART;
    const float* qr = pq + (size_t)c * NPART;
    float s = 0.f, q = 0.f;
    for (int i = tid; i < NPART; i += 256) { s += pr[i]; q += qr[i]; }
    #pragma unroll
    for (int off = 1; off < 64; off <<= 1) { s += __shfl_xor(s, off); q += __shfl_xor(q, off); }
    __shared__ float ls[4], lq[4];
    const int wv = tid >> 6;
    if ((tid & 63) == 0) { ls[wv] = s; lq[wv] = q; }
    __syncthreads();
    if (tid == 0) {
        const float S = ls[0] + ls[1] + ls[2] + ls[3];
        const float Q = lq[0] + lq[1] + lq[2] + lq[3];
        const float mean = S * (1.0f / NN);
        const float var  = Q * (1.0f / NN) - mean * mean;
        const float rs = rsqrtf(var + 1e-5f);
        const float scale = g[c] * rs;
        sc[c] = scale;
        sh[c] = beta[c] - mean * scale;
    }
}

// ---------------- GEMM2: v = relu(BN1(t)) @ W2, + BN2 partial stats ----------------
__global__ __launch_bounds__(128) void k_gemmD(
    const unsigned short* __restrict__ t_bf,
    const float* __restrict__ sc1, const float* __restrict__ sh1,
    const unsigned short* __restrict__ Wp,
    float* __restrict__ vbuf,
    float* __restrict__ ps, float* __restrict__ pq)
{
    __shared__ __align__(16) unsigned short us[16 * 264];
    const int tid = threadIdx.x;
    const int r0 = blockIdx.x * 16;
    {
        const int row = tid & 15, g8 = (tid >> 4) * 8;
        #pragma unroll
        for (int cc = 0; cc < 4; ++cc) {
            const int c = cc * 64 + g8;
            union { bf16x8 v; unsigned short u[8]; } in, o;
            in.v = *(const bf16x8*)(t_bf + (size_t)(r0 + row) * 256 + c);
            const float4* scp = (const float4*)(sc1 + c);
            const float4* shp = (const float4*)(sh1 + c);
            const float4 s0 = scp[0], s1 = scp[1], b0 = shp[0], b1 = shp[1];
            float xv;
            xv = bf2f(in.u[0])*s0.x + b0.x; o.u[0] = f2bf(xv > 0.f ? xv : 0.f);
            xv = bf2f(in.u[1])*s0.y + b0.y; o.u[1] = f2bf(xv > 0.f ? xv : 0.f);
            xv = bf2f(in.u[2])*s0.z + b0.z; o.u[2] = f2bf(xv > 0.f ? xv : 0.f);
            xv = bf2f(in.u[3])*s0.w + b0.w; o.u[3] = f2bf(xv > 0.f ? xv : 0.f);
            xv = bf2f(in.u[4])*s1.x + b1.x; o.u[4] = f2bf(xv > 0.f ? xv : 0.f);
            xv = bf2f(in.u[5])*s1.y + b1.y; o.u[5] = f2bf(xv > 0.f ? xv : 0.f);
            xv = bf2f(in.u[6])*s1.z + b1.z; o.u[6] = f2bf(xv > 0.f ? xv : 0.f);
            xv = bf2f(in.u[7])*s1.w + b1.w; o.u[7] = f2bf(xv > 0.f ? xv : 0.f);
            *(bf16x8*)(&us[row * 264 + c]) = o.v;
        }
    }
    __syncthreads();
    const int w = tid >> 6, l6 = tid & 63, m = l6 & 15, quad = l6 >> 4;
    const f32x4 z4 = {0.f, 0.f, 0.f, 0.f};
    f32x4 acc[4] = {z4, z4, z4, z4};
    const bf16x8* Wv = (const bf16x8*)Wp;
    #pragma unroll
    for (int kt = 0; kt < 8; ++kt) {
        const bf16x8 a = *(const bf16x8*)(&us[m * 264 + kt * 32 + quad * 8]);
        #pragma unroll
        for (int f = 0; f < 4; ++f) {
            const bf16x8 b = Wv[((w * 4 + f) * 8 + kt) * 64 + l6];
            acc[f] = __builtin_amdgcn_mfma_f32_16x16x32_bf16(a, b, acc[f], 0, 0, 0);
        }
    }
    const int rowb = r0 + quad * 4;
    #pragma unroll
    for (int f = 0; f < 4; ++f) {
        const int col = w * 64 + f * 16 + m;
        float ssum = 0.f, ssq = 0.f;
        #pragma unroll
        for (int r = 0; r < 4; ++r) {
            const float val = acc[f][r];
            vbuf[(size_t)(rowb + r) * 128 + col] = val;
            ssum += val; ssq += val * val;
        }
        ssum += __shfl_xor(ssum, 16); ssum += __shfl_xor(ssum, 32);
        ssq  += __shfl_xor(ssq , 16); ssq  += __shfl_xor(ssq , 32);
        if (quad == 0) {
            ps[(size_t)col * NPART + blockIdx.x] = ssum;
            pq[(size_t)col * NPART + blockIdx.x] = ssq;
        }
    }
}

// ---------------- BN2 + optional relu + residual ----------------
__global__ void k_fin(const float* __restrict__ vbuf, const float* __restrict__ sc2,
                      const float* __restrict__ sh2, float* __restrict__ h, const int do_relu)
{
    const int t = blockIdx.x * 256 + threadIdx.x;   // grid exactly N*128
    const int c = t & 127;
    float z = vbuf[t] * sc2[c] + sh2[c];
    if (do_relu) z = z > 0.f ? z : 0.f;
    h[t] += z;
}

extern "C" void kernel_launch(void* const* d_in, const int* in_sizes, int n_in,
                              void* d_out, int out_size, void* d_ws, size_t ws_size,
                              hipStream_t stream)
{
    const float* x       = (const float*)d_in[0];
    const int*   ei      = (const int*)  d_in[1];
    const float* ea      = (const float*)d_in[2];
    const float* W_node  = (const float*)d_in[3];
    const float* b_node  = (const float*)d_in[4];
    const float* We      = (const float*)d_in[5];
    const float* be      = (const float*)d_in[6];
    const float* eps_gin = (const float*)d_in[7];
    const float* W1      = (const float*)d_in[8];
    // d_in[9] = b1: cancels exactly under BN1 (mean subtraction)
    const float* g1      = (const float*)d_in[10];
    const float* beta1   = (const float*)d_in[11];
    const float* W2      = (const float*)d_in[12];
    // d_in[13] = b2: cancels exactly under BN2
    const float* g_bn    = (const float*)d_in[14];
    const float* beta_bn = (const float*)d_in[15];

    float* h = (float*)d_out;

    char* W = (char*)d_ws;
    int*   counts  = (int*)  (W + 0);            // 200000 B (also fill cursor)
    int*   row_ptr = (int*)  (W + 200000);       // 200016 B
    float* sc1     = (float*)(W + 400016);       // 1024 B
    float* sh1     = (float*)(W + 401040);       // 1024 B
    float* sc2     = (float*)(W + 402064);       // 512 B
    float* sh2     = (float*)(W + 402576);       // 512 B
    float* ps1     = (float*)(W + 403088);       // 256*3125*4 = 3200000 B
    float* pq1     = (float*)(W + 3603088);      // 3200000 B
    float* ps2     = (float*)(W + 6803088);      // 128*3125*4 = 1600000 B
    float* pq2     = (float*)(W + 8403088);      // 1600000 B
    int2*  eidsrc  = (int2*) (W + 10003088);     // 6400000 B
    unsigned short* Wp1 = (unsigned short*)(W + 16403088);  // 327680 B
    unsigned short* Wp2 = (unsigned short*)(W + 16730768);  // 327680 B
    float* agg     = (float*)(W + 17058448);     // 25600000 B
    unsigned short* t_bf = (unsigned short*)(W + 42658448); // 25600000 B
    float* vbuf    = (float*)(W + 68258448);     // 25600000 B -> total ~93.9 MB

    (void)hipMemsetAsync(counts, 0, 200000, stream);

    k_node_enc<<<dim3(NN * DD / 256), dim3(256), 0, stream>>>(x, W_node, b_node, h);
    k_count<<<dim3(EE / 256), dim3(256), 0, stream>>>(ei, counts);
    k_scan<<<dim3(1), dim3(1024), 0, stream>>>(counts, row_ptr);
    k_fill<<<dim3(EE / 256), dim3(256), 0, stream>>>(ei, counts, eidsrc);
    k_pack<<<dim3(2 * LL * 32768 / 256), dim3(256), 0, stream>>>(W1, W2, Wp1, Wp2);

    for (int l = 0; l < LL; ++l) {
        k_agg<<<dim3(NN), dim3(128), 0, stream>>>(
            h, ea, We + (size_t)l * FF * DD, be + (size_t)l * DD, row_ptr, eidsrc, agg);
        k_gemmB<<<dim3(NPART), dim3(256), 0, stream>>>(
            h, agg, eps_gin, l, Wp1 + (size_t)l * 32768, t_bf, ps1, pq1);
        k_bnstat<<<dim3(256), dim3(256), 0, stream>>>(
            ps1, pq1, g1 + (size_t)l * 256, beta1 + (size_t)l * 256, sc1, sh1);
        k_gemmD<<<dim3(NPART), dim3(128), 0, stream>>>(
            t_bf, sc1, sh1, Wp2 + (size_t)l * 32768, vbuf, ps2, pq2);
        k_bnstat<<<dim3(128), dim3(256), 0, stream>>>(
            ps2, pq2, g_bn + (size_t)l * 128, beta_bn + (size_t)l * 128, sc2, sh2);
        k_fin<<<dim3(NN * DD / 256), dim3(256), 0, stream>>>(vbuf, sc2, sh2, h, (l < LL - 1) ? 1 : 0);
    }
}

// Round 3
// 1053.268 us; speedup vs baseline: 1.2539x; 1.1556x over previous
//
#include <hip/hip_runtime.h>
#include <hip/hip_bf16.h>

// Problem constants
#define NN 50000
#define EE 800000
#define DD 128
#define FF 16
#define LL 5
#define NPART 3125   // row-tile blocks in GEMMs (50000/16)

typedef __attribute__((ext_vector_type(8))) short bf16x8;
typedef __attribute__((ext_vector_type(4))) float f32x4;

__device__ __forceinline__ unsigned short f2bf(float f) {
    union { float f; unsigned int u; } v; v.f = f;
    unsigned int u = v.u;
    unsigned int r = (u + 0x7fffu + ((u >> 16) & 1u)) >> 16;
    return (unsigned short)r;
}
__device__ __forceinline__ float bf2f(unsigned short s) {
    union { unsigned int u; float f; } v; v.u = ((unsigned int)s) << 16;
    return v.f;
}

// ---------------- node encoder: h = x @ W_node + b_node ----------------
__global__ void k_node_enc(const float* __restrict__ x, const float* __restrict__ Wn,
                           const float* __restrict__ bn, float* __restrict__ h)
{
    const int t = blockIdx.x * 256 + threadIdx.x;   // grid exactly N*128
    const int i = t >> 7, d = t & 127;
    const float4* x4 = (const float4*)(x + (size_t)i * 16);
    float4 a0 = x4[0], a1 = x4[1], a2 = x4[2], a3 = x4[3];
    float acc = bn[d];
    acc += a0.x*Wn[0*128+d] + a0.y*Wn[1*128+d] + a0.z*Wn[2*128+d] + a0.w*Wn[3*128+d];
    acc += a1.x*Wn[4*128+d] + a1.y*Wn[5*128+d] + a1.z*Wn[6*128+d] + a1.w*Wn[7*128+d];
    acc += a2.x*Wn[8*128+d] + a2.y*Wn[9*128+d] + a2.z*Wn[10*128+d] + a2.w*Wn[11*128+d];
    acc += a3.x*Wn[12*128+d] + a3.y*Wn[13*128+d] + a3.z*Wn[14*128+d] + a3.w*Wn[15*128+d];
    h[t] = acc;
}

// ---------------- CSR build ----------------
__global__ void k_count(const int* __restrict__ ei, int* __restrict__ counts)
{
    const int e = blockIdx.x * 256 + threadIdx.x;   // grid exactly E
    atomicAdd(&counts[ei[EE + e]], 1);
}

// Wave-shuffle scan: 3 barriers/tile instead of 20 (R2).
__global__ __launch_bounds__(1024) void k_scan(int* __restrict__ counts, int* __restrict__ row_ptr)
{
    __shared__ int wsum[16];
    __shared__ int carry;
    const int tid = threadIdx.x, lane = tid & 63, w = tid >> 6;
    if (tid == 0) carry = 0;
    __syncthreads();
    for (int base = 0; base < NN; base += 1024) {
        const int i = base + tid;
        const int v = (i < NN) ? counts[i] : 0;
        int x = v;
        #pragma unroll
        for (int off = 1; off < 64; off <<= 1) {
            const int t = __shfl_up(x, off);
            if (lane >= off) x += t;
        }
        if (lane == 63) wsum[w] = x;
        __syncthreads();                       // wsum ready
        int woff = 0, total = 0;
        #pragma unroll
        for (int j = 0; j < 16; ++j) { const int s = wsum[j]; total += s; if (j < w) woff += s; }
        const int ex = carry + woff + x - v;
        if (i < NN) { row_ptr[i] = ex; counts[i] = ex; }
        __syncthreads();                       // everyone has read carry/wsum
        if (tid == 0) carry += total;
        __syncthreads();                       // carry updated, wsum reusable
    }
    if (tid == 0) row_ptr[NN] = carry;
}

__global__ void k_fill(const int* __restrict__ ei, int* __restrict__ cursor, int2* __restrict__ eidsrc)
{
    const int e = blockIdx.x * 256 + threadIdx.x;   // grid exactly E
    const int d = ei[EE + e];
    const int p = atomicAdd(&cursor[d], 1);
    eidsrc[p] = make_int2(e, ei[e]);
}

// ---------------- weight repack to MFMA B-fragment layout ----------------
// B-frag (16x16x32 bf16): lane holds B[k0 + (lane>>4)*8 + j][n0 + (lane&15)], j=0..7
__global__ void k_pack(const float* __restrict__ W1, const float* __restrict__ W2,
                       unsigned short* __restrict__ Wp1, unsigned short* __restrict__ Wp2)
{
    int t = blockIdx.x * 256 + threadIdx.x;   // grid exactly 2*L*32768
    const int total = LL * 32768;
    if (t < total) {
        const int l = t >> 15, r = t & 32767;
        const int j = r & 7, lane = (r >> 3) & 63, kt = (r >> 9) & 3, nt = r >> 11;
        const int k = kt * 32 + (lane >> 4) * 8 + j;
        const int n = nt * 16 + (lane & 15);
        Wp1[t] = f2bf(W1[(size_t)l * 32768 + k * 256 + n]);
    } else {
        t -= total;
        const int l = t >> 15, r = t & 32767;
        const int j = r & 7, lane = (r >> 3) & 63, kt = (r >> 9) & 7, nt = r >> 12;
        const int k = kt * 32 + (lane >> 4) * 8 + j;
        const int n = nt * 16 + (lane & 15);
        Wp2[t] = f2bf(W2[(size_t)l * 32768 + k * 128 + n]);
    }
}

// ---------------- fused edge-encode + gather + CSR aggregate ----------------
// R2: one wave per node (lane owns 2 channels, float2), 4-edge groups with
// software-pipelined eidsrc prefetch (next group's index loads issued before
// this group's compute). ea rows via readfirstlane -> scalar K$ loads.
__global__ __launch_bounds__(256) void k_agg(
    const float* __restrict__ h, const float* __restrict__ ea,
    const float* __restrict__ We_l, const float* __restrict__ be_l,
    const int* __restrict__ row_ptr, const int2* __restrict__ eidsrc,
    float* __restrict__ agg)
{
    const int wv = threadIdx.x >> 6;
    const int v  = blockIdx.x * 4 + wv;      // grid exactly N/4 blocks
    const int lane = threadIdx.x & 63;
    const int c2 = lane * 2;
    float2 w[16];
    #pragma unroll
    for (int f = 0; f < 16; ++f) w[f] = *(const float2*)(We_l + f * 128 + c2);
    const float2 bed = *(const float2*)(be_l + c2);
    const int kbeg = __builtin_amdgcn_readfirstlane(row_ptr[v]);
    const int kend = __builtin_amdgcn_readfirstlane(row_ptr[v + 1]);
    float2 acc0 = {0.f, 0.f}, acc1 = {0.f, 0.f}, acc2 = {0.f, 0.f}, acc3 = {0.f, 0.f};

#define EDGE_DOT(eidx_, hs_, out_) do {                                        \
        const float4* p_ = (const float4*)(ea + (size_t)(eidx_) * 16);         \
        const float4 a0_ = p_[0], a1_ = p_[1], a2_ = p_[2], a3_ = p_[3];       \
        float ex_ = bed.x, ey_ = bed.y;                                        \
        ex_ += a0_.x*w[0].x  + a0_.y*w[1].x  + a0_.z*w[2].x  + a0_.w*w[3].x;   \
        ey_ += a0_.x*w[0].y  + a0_.y*w[1].y  + a0_.z*w[2].y  + a0_.w*w[3].y;   \
        ex_ += a1_.x*w[4].x  + a1_.y*w[5].x  + a1_.z*w[6].x  + a1_.w*w[7].x;   \
        ey_ += a1_.x*w[4].y  + a1_.y*w[5].y  + a1_.z*w[6].y  + a1_.w*w[7].y;   \
        ex_ += a2_.x*w[8].x  + a2_.y*w[9].x  + a2_.z*w[10].x + a2_.w*w[11].x;  \
        ey_ += a2_.x*w[8].y  + a2_.y*w[9].y  + a2_.z*w[10].y + a2_.w*w[11].y;  \
        ex_ += a3_.x*w[12].x + a3_.y*w[13].x + a3_.z*w[14].x + a3_.w*w[15].x;  \
        ey_ += a3_.x*w[12].y + a3_.y*w[13].y + a3_.z*w[14].y + a3_.w*w[15].y;  \
        const float mx_ = hs_.x + ex_, my_ = hs_.y + ey_;                      \
        (out_).x += mx_ > 0.f ? mx_ : 0.f;                                     \
        (out_).y += my_ > 0.f ? my_ : 0.f;                                     \
    } while (0)

    int k = kbeg;
    int2 q0, q1, q2, q3;
    bool have = (k + 4 <= kend);
    if (have) { q0 = eidsrc[k]; q1 = eidsrc[k+1]; q2 = eidsrc[k+2]; q3 = eidsrc[k+3]; }
    while (have) {
        const int e0 = __builtin_amdgcn_readfirstlane(q0.x);
        const int s0 = __builtin_amdgcn_readfirstlane(q0.y);
        const int e1 = __builtin_amdgcn_readfirstlane(q1.x);
        const int s1 = __builtin_amdgcn_readfirstlane(q1.y);
        const int e2 = __builtin_amdgcn_readfirstlane(q2.x);
        const int s2 = __builtin_amdgcn_readfirstlane(q2.y);
        const int e3 = __builtin_amdgcn_readfirstlane(q3.x);
        const int s3 = __builtin_amdgcn_readfirstlane(q3.y);
        const float2 h0 = *(const float2*)(h + (size_t)s0 * 128 + c2);
        const float2 h1 = *(const float2*)(h + (size_t)s1 * 128 + c2);
        const float2 h2 = *(const float2*)(h + (size_t)s2 * 128 + c2);
        const float2 h3 = *(const float2*)(h + (size_t)s3 * 128 + c2);
        const int kn = k + 4;
        const bool haven = (kn + 4 <= kend);
        int2 n0, n1, n2, n3;
        if (haven) { n0 = eidsrc[kn]; n1 = eidsrc[kn+1]; n2 = eidsrc[kn+2]; n3 = eidsrc[kn+3]; }
        EDGE_DOT(e0, h0, acc0);
        EDGE_DOT(e1, h1, acc1);
        EDGE_DOT(e2, h2, acc2);
        EDGE_DOT(e3, h3, acc3);
        q0 = n0; q1 = n1; q2 = n2; q3 = n3;
        k = kn; have = haven;
    }
    for (; k < kend; ++k) {
        const int2 q = eidsrc[k];
        const int e0 = __builtin_amdgcn_readfirstlane(q.x);
        const int s0 = __builtin_amdgcn_readfirstlane(q.y);
        const float2 h0 = *(const float2*)(h + (size_t)s0 * 128 + c2);
        EDGE_DOT(e0, h0, acc0);
    }
#undef EDGE_DOT
    float2 r;
    r.x = (acc0.x + acc1.x) + (acc2.x + acc3.x);
    r.y = (acc0.y + acc1.y) + (acc2.y + acc3.y);
    *(float2*)(agg + (size_t)v * 128 + c2) = r;
}

// ---------------- GEMM1: t = ((1+eps)h + agg) @ W1, + BN1 partial stats ----------------
__global__ __launch_bounds__(256) void k_gemmB(
    const float* __restrict__ h, const float* __restrict__ agg,
    const float* __restrict__ eps_gin, const int l,
    const unsigned short* __restrict__ Wp,
    unsigned short* __restrict__ t_bf,
    float* __restrict__ ps, float* __restrict__ pq)
{
    __shared__ __align__(16) unsigned short zs[16 * 136];
    const int tid = threadIdx.x;
    const int r0 = blockIdx.x * 16;
    const float epsv = 1.0f + eps_gin[l];
    {
        const int row = tid & 15, c0 = (tid >> 4) * 8;
        const float4* hp = (const float4*)(h   + (size_t)(r0 + row) * 128 + c0);
        const float4* ap = (const float4*)(agg + (size_t)(r0 + row) * 128 + c0);
        const float4 h0 = hp[0], h1 = hp[1], a0 = ap[0], a1 = ap[1];
        union { bf16x8 v; unsigned short u[8]; } pk;
        pk.u[0] = f2bf(epsv*h0.x + a0.x);
        pk.u[1] = f2bf(epsv*h0.y + a0.y);
        pk.u[2] = f2bf(epsv*h0.z + a0.z);
        pk.u[3] = f2bf(epsv*h0.w + a0.w);
        pk.u[4] = f2bf(epsv*h1.x + a1.x);
        pk.u[5] = f2bf(epsv*h1.y + a1.y);
        pk.u[6] = f2bf(epsv*h1.z + a1.z);
        pk.u[7] = f2bf(epsv*h1.w + a1.w);
        *(bf16x8*)(&zs[row * 136 + c0]) = pk.v;
    }
    __syncthreads();
    const int w = tid >> 6, l6 = tid & 63, m = l6 & 15, quad = l6 >> 4;
    const f32x4 z4 = {0.f, 0.f, 0.f, 0.f};
    f32x4 acc[4] = {z4, z4, z4, z4};
    const bf16x8* Wv = (const bf16x8*)Wp;
    #pragma unroll
    for (int kt = 0; kt < 4; ++kt) {
        const bf16x8 a = *(const bf16x8*)(&zs[m * 136 + kt * 32 + quad * 8]);
        #pragma unroll
        for (int f = 0; f < 4; ++f) {
            const bf16x8 b = Wv[((w * 4 + f) * 4 + kt) * 64 + l6];
            acc[f] = __builtin_amdgcn_mfma_f32_16x16x32_bf16(a, b, acc[f], 0, 0, 0);
        }
    }
    const int rowb = r0 + quad * 4;
    #pragma unroll
    for (int f = 0; f < 4; ++f) {
        const int col = w * 64 + f * 16 + m;
        float ssum = 0.f, ssq = 0.f;
        #pragma unroll
        for (int r = 0; r < 4; ++r) {
            const float val = acc[f][r];
            t_bf[(size_t)(rowb + r) * 256 + col] = f2bf(val);
            ssum += val; ssq += val * val;
        }
        ssum += __shfl_xor(ssum, 16); ssum += __shfl_xor(ssum, 32);
        ssq  += __shfl_xor(ssq , 16); ssq  += __shfl_xor(ssq , 32);
        if (quad == 0) {
            ps[(size_t)col * NPART + blockIdx.x] = ssum;
            pq[(size_t)col * NPART + blockIdx.x] = ssq;
        }
    }
}

// ---------------- BN stat fold: per-channel scale/shift ----------------
__global__ void k_bnstat(const float* __restrict__ ps, const float* __restrict__ pq,
                         const float* __restrict__ g, const float* __restrict__ beta,
                         float* __restrict__ sc, float* __restrict__ sh)
{
    const int c = blockIdx.x;
    const int tid = threadIdx.x;   // 256 threads
    const float* pr = ps + (size_t)c * NPART;
    const float* qr = pq + (size_t)c * NPART;
    float s = 0.f, q = 0.f;
    for (int i = tid; i < NPART; i += 256) { s += pr[i]; q += qr[i]; }
    #pragma unroll
    for (int off = 1; off < 64; off <<= 1) { s += __shfl_xor(s, off); q += __shfl_xor(q, off); }
    __shared__ float ls[4], lq[4];
    const int wv = tid >> 6;
    if ((tid & 63) == 0) { ls[wv] = s; lq[wv] = q; }
    __syncthreads();
    if (tid == 0) {
        const float S = ls[0] + ls[1] + ls[2] + ls[3];
        const float Q = lq[0] + lq[1] + lq[2] + lq[3];
        const float mean = S * (1.0f / NN);
        const float var  = Q * (1.0f / NN) - mean * mean;
        const float rs = rsqrtf(var + 1e-5f);
        const float scale = g[c] * rs;
        sc[c] = scale;
        sh[c] = beta[c] - mean * scale;
    }
}

// ---------------- GEMM2: v = relu(BN1(t)) @ W2, + BN2 partial stats ----------------
__global__ __launch_bounds__(128) void k_gemmD(
    const unsigned short* __restrict__ t_bf,
    const float* __restrict__ sc1, const float* __restrict__ sh1,
    const unsigned short* __restrict__ Wp,
    float* __restrict__ vbuf,
    float* __restrict__ ps, float* __restrict__ pq)
{
    __shared__ __align__(16) unsigned short us[16 * 264];
    const int tid = threadIdx.x;
    const int r0 = blockIdx.x * 16;
    {
        const int row = tid & 15, g8 = (tid >> 4) * 8;
        #pragma unroll
        for (int cc = 0; cc < 4; ++cc) {
            const int c = cc * 64 + g8;
            union { bf16x8 v; unsigned short u[8]; } in, o;
            in.v = *(const bf16x8*)(t_bf + (size_t)(r0 + row) * 256 + c);
            const float4* scp = (const float4*)(sc1 + c);
            const float4* shp = (const float4*)(sh1 + c);
            const float4 s0 = scp[0], s1 = scp[1], b0 = shp[0], b1 = shp[1];
            float xv;
            xv = bf2f(in.u[0])*s0.x + b0.x; o.u[0] = f2bf(xv > 0.f ? xv : 0.f);
            xv = bf2f(in.u[1])*s0.y + b0.y; o.u[1] = f2bf(xv > 0.f ? xv : 0.f);
            xv = bf2f(in.u[2])*s0.z + b0.z; o.u[2] = f2bf(xv > 0.f ? xv : 0.f);
            xv = bf2f(in.u[3])*s0.w + b0.w; o.u[3] = f2bf(xv > 0.f ? xv : 0.f);
            xv = bf2f(in.u[4])*s1.x + b1.x; o.u[4] = f2bf(xv > 0.f ? xv : 0.f);
            xv = bf2f(in.u[5])*s1.y + b1.y; o.u[5] = f2bf(xv > 0.f ? xv : 0.f);
            xv = bf2f(in.u[6])*s1.z + b1.z; o.u[6] = f2bf(xv > 0.f ? xv : 0.f);
            xv = bf2f(in.u[7])*s1.w + b1.w; o.u[7] = f2bf(xv > 0.f ? xv : 0.f);
            *(bf16x8*)(&us[row * 264 + c]) = o.v;
        }
    }
    __syncthreads();
    const int w = tid >> 6, l6 = tid & 63, m = l6 & 15, quad = l6 >> 4;
    const f32x4 z4 = {0.f, 0.f, 0.f, 0.f};
    f32x4 acc[4] = {z4, z4, z4, z4};
    const bf16x8* Wv = (const bf16x8*)Wp;
    #pragma unroll
    for (int kt = 0; kt < 8; ++kt) {
        const bf16x8 a = *(const bf16x8*)(&us[m * 264 + kt * 32 + quad * 8]);
        #pragma unroll
        for (int f = 0; f < 4; ++f) {
            const bf16x8 b = Wv[((w * 4 + f) * 8 + kt) * 64 + l6];
            acc[f] = __builtin_amdgcn_mfma_f32_16x16x32_bf16(a, b, acc[f], 0, 0, 0);
        }
    }
    const int rowb = r0 + quad * 4;
    #pragma unroll
    for (int f = 0; f < 4; ++f) {
        const int col = w * 64 + f * 16 + m;
        float ssum = 0.f, ssq = 0.f;
        #pragma unroll
        for (int r = 0; r < 4; ++r) {
            const float val = acc[f][r];
            vbuf[(size_t)(rowb + r) * 128 + col] = val;
            ssum += val; ssq += val * val;
        }
        ssum += __shfl_xor(ssum, 16); ssum += __shfl_xor(ssum, 32);
        ssq  += __shfl_xor(ssq , 16); ssq  += __shfl_xor(ssq , 32);
        if (quad == 0) {
            ps[(size_t)col * NPART + blockIdx.x] = ssum;
            pq[(size_t)col * NPART + blockIdx.x] = ssq;
        }
    }
}

// ---------------- BN2 + optional relu + residual ----------------
__global__ void k_fin(const float* __restrict__ vbuf, const float* __restrict__ sc2,
                      const float* __restrict__ sh2, float* __restrict__ h, const int do_relu)
{
    const int t = blockIdx.x * 256 + threadIdx.x;   // grid exactly N*128
    const int c = t & 127;
    float z = vbuf[t] * sc2[c] + sh2[c];
    if (do_relu) z = z > 0.f ? z : 0.f;
    h[t] += z;
}

extern "C" void kernel_launch(void* const* d_in, const int* in_sizes, int n_in,
                              void* d_out, int out_size, void* d_ws, size_t ws_size,
                              hipStream_t stream)
{
    const float* x       = (const float*)d_in[0];
    const int*   ei      = (const int*)  d_in[1];
    const float* ea      = (const float*)d_in[2];
    const float* W_node  = (const float*)d_in[3];
    const float* b_node  = (const float*)d_in[4];
    const float* We      = (const float*)d_in[5];
    const float* be      = (const float*)d_in[6];
    const float* eps_gin = (const float*)d_in[7];
    const float* W1      = (const float*)d_in[8];
    // d_in[9] = b1: cancels exactly under BN1 (mean subtraction)
    const float* g1      = (const float*)d_in[10];
    const float* beta1   = (const float*)d_in[11];
    const float* W2      = (const float*)d_in[12];
    // d_in[13] = b2: cancels exactly under BN2
    const float* g_bn    = (const float*)d_in[14];
    const float* beta_bn = (const float*)d_in[15];

    float* h = (float*)d_out;

    char* W = (char*)d_ws;
    int*   counts  = (int*)  (W + 0);            // 200000 B (also fill cursor)
    int*   row_ptr = (int*)  (W + 200000);       // 200016 B
    float* sc1     = (float*)(W + 400016);       // 1024 B
    float* sh1     = (float*)(W + 401040);       // 1024 B
    float* sc2     = (float*)(W + 402064);       // 512 B
    float* sh2     = (float*)(W + 402576);       // 512 B
    float* ps1     = (float*)(W + 403088);       // 256*3125*4 = 3200000 B
    float* pq1     = (float*)(W + 3603088);      // 3200000 B
    float* ps2     = (float*)(W + 6803088);      // 128*3125*4 = 1600000 B
    float* pq2     = (float*)(W + 8403088);      // 1600000 B
    int2*  eidsrc  = (int2*) (W + 10003088);     // 6400000 B
    unsigned short* Wp1 = (unsigned short*)(W + 16403088);  // 327680 B
    unsigned short* Wp2 = (unsigned short*)(W + 16730768);  // 327680 B
    float* agg     = (float*)(W + 17058448);     // 25600000 B
    unsigned short* t_bf = (unsigned short*)(W + 42658448); // 25600000 B
    float* vbuf    = (float*)(W + 68258448);     // 25600000 B -> total ~93.9 MB

    (void)hipMemsetAsync(counts, 0, 200000, stream);

    k_node_enc<<<dim3(NN * DD / 256), dim3(256), 0, stream>>>(x, W_node, b_node, h);
    k_count<<<dim3(EE / 256), dim3(256), 0, stream>>>(ei, counts);
    k_scan<<<dim3(1), dim3(1024), 0, stream>>>(counts, row_ptr);
    k_fill<<<dim3(EE / 256), dim3(256), 0, stream>>>(ei, counts, eidsrc);
    k_pack<<<dim3(2 * LL * 32768 / 256), dim3(256), 0, stream>>>(W1, W2, Wp1, Wp2);

    for (int l = 0; l < LL; ++l) {
        k_agg<<<dim3(NN / 4), dim3(256), 0, stream>>>(
            h, ea, We + (size_t)l * FF * DD, be + (size_t)l * DD, row_ptr, eidsrc, agg);
        k_gemmB<<<dim3(NPART), dim3(256), 0, stream>>>(
            h, agg, eps_gin, l, Wp1 + (size_t)l * 32768, t_bf, ps1, pq1);
        k_bnstat<<<dim3(256), dim3(256), 0, stream>>>(
            ps1, pq1, g1 + (size_t)l * 256, beta1 + (size_t)l * 256, sc1, sh1);
        k_gemmD<<<dim3(NPART), dim3(128), 0, stream>>>(
            t_bf, sc1, sh1, Wp2 + (size_t)l * 32768, vbuf, ps2, pq2);
        k_bnstat<<<dim3(128), dim3(256), 0, stream>>>(
            ps2, pq2, g_bn + (size_t)l * 128, beta_bn + (size_t)l * 128, sc2, sh2);
        k_fin<<<dim3(NN * DD / 256), dim3(256), 0, stream>>>(vbuf, sc2, sh2, h, (l < LL - 1) ? 1 : 0);
    }
}

// Round 4
// 949.935 us; speedup vs baseline: 1.3903x; 1.1088x over previous
//
#include <hip/hip_runtime.h>
#include <hip/hip_bf16.h>

// Problem constants
#define NN 50000
#define EE 800000
#define DD 128
#define FF 16
#define LL 5
#define NPART 3125   // row-tile blocks in GEMMs (50000/16)

typedef __attribute__((ext_vector_type(8))) short bf16x8;
typedef __attribute__((ext_vector_type(4))) float f32x4;

__device__ __forceinline__ unsigned short f2bf(float f) {
    union { float f; unsigned int u; } v; v.f = f;
    unsigned int u = v.u;
    unsigned int r = (u + 0x7fffu + ((u >> 16) & 1u)) >> 16;
    return (unsigned short)r;
}
__device__ __forceinline__ float bf2f(unsigned short s) {
    union { unsigned int u; float f; } v; v.u = ((unsigned int)s) << 16;
    return v.f;
}
#define BFLO(u) __uint_as_float((unsigned int)(u) << 16)
#define BFHI(u) __uint_as_float((unsigned int)(u) & 0xffff0000u)

// ---------------- node encoder: h = x @ W_node + b_node (+ bf16 mirror) ----------------
__global__ void k_node_enc(const float* __restrict__ x, const float* __restrict__ Wn,
                           const float* __restrict__ bn, float* __restrict__ h,
                           unsigned short* __restrict__ h_bf)
{
    const int t = blockIdx.x * 256 + threadIdx.x;   // grid exactly N*128
    const int i = t >> 7, d = t & 127;
    const float4* x4 = (const float4*)(x + (size_t)i * 16);
    float4 a0 = x4[0], a1 = x4[1], a2 = x4[2], a3 = x4[3];
    float acc = bn[d];
    acc += a0.x*Wn[0*128+d] + a0.y*Wn[1*128+d] + a0.z*Wn[2*128+d] + a0.w*Wn[3*128+d];
    acc += a1.x*Wn[4*128+d] + a1.y*Wn[5*128+d] + a1.z*Wn[6*128+d] + a1.w*Wn[7*128+d];
    acc += a2.x*Wn[8*128+d] + a2.y*Wn[9*128+d] + a2.z*Wn[10*128+d] + a2.w*Wn[11*128+d];
    acc += a3.x*Wn[12*128+d] + a3.y*Wn[13*128+d] + a3.z*Wn[14*128+d] + a3.w*Wn[15*128+d];
    h[t] = acc;
    h_bf[t] = f2bf(acc);
}

// ---------------- CSR build ----------------
__global__ void k_count(const int* __restrict__ ei, int* __restrict__ counts)
{
    const int e = blockIdx.x * 256 + threadIdx.x;   // grid exactly E
    atomicAdd(&counts[ei[EE + e]], 1);
}

// Wave-shuffle scan: 3 barriers/tile (R2).
__global__ __launch_bounds__(1024) void k_scan(int* __restrict__ counts, int* __restrict__ row_ptr)
{
    __shared__ int wsum[16];
    __shared__ int carry;
    const int tid = threadIdx.x, lane = tid & 63, w = tid >> 6;
    if (tid == 0) carry = 0;
    __syncthreads();
    for (int base = 0; base < NN; base += 1024) {
        const int i = base + tid;
        const int v = (i < NN) ? counts[i] : 0;
        int x = v;
        #pragma unroll
        for (int off = 1; off < 64; off <<= 1) {
            const int t = __shfl_up(x, off);
            if (lane >= off) x += t;
        }
        if (lane == 63) wsum[w] = x;
        __syncthreads();
        int woff = 0, total = 0;
        #pragma unroll
        for (int j = 0; j < 16; ++j) { const int s = wsum[j]; total += s; if (j < w) woff += s; }
        const int ex = carry + woff + x - v;
        if (i < NN) { row_ptr[i] = ex; counts[i] = ex; }
        __syncthreads();
        if (tid == 0) carry += total;
        __syncthreads();
    }
    if (tid == 0) row_ptr[NN] = carry;
}

// R3: fill CSR slots AND permute+convert edge features to bf16 in CSR order,
// so k_agg streams edge rows sequentially with zero indirection.
__global__ void k_fill(const int* __restrict__ ei, const float* __restrict__ ea,
                       int* __restrict__ cursor, int* __restrict__ src_perm,
                       unsigned short* __restrict__ ea_bf)
{
    const int e = blockIdx.x * 256 + threadIdx.x;   // grid exactly E
    const int dst = ei[EE + e];
    const int p = atomicAdd(&cursor[dst], 1);
    src_perm[p] = ei[e];
    const float4* s4 = (const float4*)(ea + (size_t)e * 16);
    const float4 a0 = s4[0], a1 = s4[1], a2 = s4[2], a3 = s4[3];
    union { bf16x8 v; unsigned short u[8]; } o0, o1;
    o0.u[0]=f2bf(a0.x); o0.u[1]=f2bf(a0.y); o0.u[2]=f2bf(a0.z); o0.u[3]=f2bf(a0.w);
    o0.u[4]=f2bf(a1.x); o0.u[5]=f2bf(a1.y); o0.u[6]=f2bf(a1.z); o0.u[7]=f2bf(a1.w);
    o1.u[0]=f2bf(a2.x); o1.u[1]=f2bf(a2.y); o1.u[2]=f2bf(a2.z); o1.u[3]=f2bf(a2.w);
    o1.u[4]=f2bf(a3.x); o1.u[5]=f2bf(a3.y); o1.u[6]=f2bf(a3.z); o1.u[7]=f2bf(a3.w);
    bf16x8* dp = (bf16x8*)(ea_bf + (size_t)p * 16);
    dp[0] = o0.v; dp[1] = o1.v;
}

// ---------------- weight repack to MFMA B-fragment layout ----------------
__global__ void k_pack(const float* __restrict__ W1, const float* __restrict__ W2,
                       unsigned short* __restrict__ Wp1, unsigned short* __restrict__ Wp2)
{
    int t = blockIdx.x * 256 + threadIdx.x;   // grid exactly 2*L*32768
    const int total = LL * 32768;
    if (t < total) {
        const int l = t >> 15, r = t & 32767;
        const int j = r & 7, lane = (r >> 3) & 63, kt = (r >> 9) & 3, nt = r >> 11;
        const int k = kt * 32 + (lane >> 4) * 8 + j;
        const int n = nt * 16 + (lane & 15);
        Wp1[t] = f2bf(W1[(size_t)l * 32768 + k * 256 + n]);
    } else {
        t -= total;
        const int l = t >> 15, r = t & 32767;
        const int j = r & 7, lane = (r >> 3) & 63, kt = (r >> 9) & 7, nt = r >> 12;
        const int k = kt * 32 + (lane >> 4) * 8 + j;
        const int n = nt * 16 + (lane & 15);
        Wp2[t] = f2bf(W2[(size_t)l * 32768 + k * 128 + n]);
    }
}

// ---------------- fused edge-encode + gather + aggregate + GIN-z (bf16 out) ----------------
// R3: bf16 h gather (1 dword/lane), streamed bf16 CSR-ordered edge rows,
// depth-1 pipeline over src/ea/h; writes z = (1+eps)*h_v + agg as bf16.
__global__ __launch_bounds__(256) void k_agg(
    const unsigned short* __restrict__ h_bf, const unsigned short* __restrict__ ea_bf,
    const float* __restrict__ We_l, const float* __restrict__ be_l,
    const float* __restrict__ eps_gin, const int l,
    const int* __restrict__ row_ptr, const int* __restrict__ src_perm,
    unsigned short* __restrict__ z_bf)
{
    const int wv = threadIdx.x >> 6;
    const int v  = blockIdx.x * 4 + wv;      // grid exactly N/4 blocks
    const int lane = threadIdx.x & 63;
    const int c2 = lane * 2;
    float2 w[16];
    #pragma unroll
    for (int f = 0; f < 16; ++f) w[f] = *(const float2*)(We_l + f * 128 + c2);
    const float2 bed = *(const float2*)(be_l + c2);
    const float epsv = 1.0f + eps_gin[l];
    const int kbeg = __builtin_amdgcn_readfirstlane(row_ptr[v]);
    const int kend = __builtin_amdgcn_readfirstlane(row_ptr[v + 1]);
    float2 acc0 = {0.f,0.f}, acc1 = {0.f,0.f}, acc2 = {0.f,0.f}, acc3 = {0.f,0.f};

#define LOAD_GROUP(kk, S0,S1,S2,S3, E0,E1,E2,E3,E4,E5,E6,E7, H0,H1,H2,H3)  \
    { const int* sp_ = src_perm + (kk);                                     \
      S0 = __builtin_amdgcn_readfirstlane(sp_[0]);                          \
      S1 = __builtin_amdgcn_readfirstlane(sp_[1]);                          \
      S2 = __builtin_amdgcn_readfirstlane(sp_[2]);                          \
      S3 = __builtin_amdgcn_readfirstlane(sp_[3]);                          \
      const uint4* ep_ = (const uint4*)(ea_bf + (size_t)(kk) * 16);         \
      E0 = ep_[0]; E1 = ep_[1]; E2 = ep_[2]; E3 = ep_[3];                   \
      E4 = ep_[4]; E5 = ep_[5]; E6 = ep_[6]; E7 = ep_[7];                   \
      H0 = *(const unsigned int*)(h_bf + (size_t)S0 * 128 + c2);            \
      H1 = *(const unsigned int*)(h_bf + (size_t)S1 * 128 + c2);            \
      H2 = *(const unsigned int*)(h_bf + (size_t)S2 * 128 + c2);            \
      H3 = *(const unsigned int*)(h_bf + (size_t)S3 * 128 + c2); }

#define EDGE_DOT(EA, EB, HQ, OUT) do {                                      \
        float ex_ = bed.x, ey_ = bed.y, a_;                                 \
        a_ = BFLO(EA.x); ex_ += a_*w[0].x;  ey_ += a_*w[0].y;               \
        a_ = BFHI(EA.x); ex_ += a_*w[1].x;  ey_ += a_*w[1].y;               \
        a_ = BFLO(EA.y); ex_ += a_*w[2].x;  ey_ += a_*w[2].y;               \
        a_ = BFHI(EA.y); ex_ += a_*w[3].x;  ey_ += a_*w[3].y;               \
        a_ = BFLO(EA.z); ex_ += a_*w[4].x;  ey_ += a_*w[4].y;               \
        a_ = BFHI(EA.z); ex_ += a_*w[5].x;  ey_ += a_*w[5].y;               \
        a_ = BFLO(EA.w); ex_ += a_*w[6].x;  ey_ += a_*w[6].y;               \
        a_ = BFHI(EA.w); ex_ += a_*w[7].x;  ey_ += a_*w[7].y;               \
        a_ = BFLO(EB.x); ex_ += a_*w[8].x;  ey_ += a_*w[8].y;               \
        a_ = BFHI(EB.x); ex_ += a_*w[9].x;  ey_ += a_*w[9].y;               \
        a_ = BFLO(EB.y); ex_ += a_*w[10].x; ey_ += a_*w[10].y;              \
        a_ = BFHI(EB.y); ex_ += a_*w[11].x; ey_ += a_*w[11].y;              \
        a_ = BFLO(EB.z); ex_ += a_*w[12].x; ey_ += a_*w[12].y;              \
        a_ = BFHI(EB.z); ex_ += a_*w[13].x; ey_ += a_*w[13].y;              \
        a_ = BFLO(EB.w); ex_ += a_*w[14].x; ey_ += a_*w[14].y;              \
        a_ = BFHI(EB.w); ex_ += a_*w[15].x; ey_ += a_*w[15].y;              \
        const float mx_ = BFLO(HQ) + ex_, my_ = BFHI(HQ) + ey_;             \
        OUT.x += mx_ > 0.f ? mx_ : 0.f;                                     \
        OUT.y += my_ > 0.f ? my_ : 0.f;                                     \
    } while (0)

    int k = kbeg;
    int cs0, cs1, cs2, cs3;
    uint4 ce0, ce1, ce2, ce3, ce4, ce5, ce6, ce7;
    unsigned int ch0, ch1, ch2, ch3;
    if (k < kend) {
        LOAD_GROUP(k, cs0,cs1,cs2,cs3, ce0,ce1,ce2,ce3,ce4,ce5,ce6,ce7, ch0,ch1,ch2,ch3);
    }
    for (; k < kend; k += 4) {
        int ns0, ns1, ns2, ns3;
        uint4 ne0, ne1, ne2, ne3, ne4, ne5, ne6, ne7;
        unsigned int nh0, nh1, nh2, nh3;
        LOAD_GROUP(k + 4, ns0,ns1,ns2,ns3, ne0,ne1,ne2,ne3,ne4,ne5,ne6,ne7, nh0,nh1,nh2,nh3);
        EDGE_DOT(ce0, ce1, ch0, acc0);
        if (k + 1 < kend) EDGE_DOT(ce2, ce3, ch1, acc1);
        if (k + 2 < kend) EDGE_DOT(ce4, ce5, ch2, acc2);
        if (k + 3 < kend) EDGE_DOT(ce6, ce7, ch3, acc3);
        cs0=ns0; cs1=ns1; cs2=ns2; cs3=ns3;
        ce0=ne0; ce1=ne1; ce2=ne2; ce3=ne3; ce4=ne4; ce5=ne5; ce6=ne6; ce7=ne7;
        ch0=nh0; ch1=nh1; ch2=nh2; ch3=nh3;
    }
#undef EDGE_DOT
#undef LOAD_GROUP
    (void)cs0; (void)cs1; (void)cs2; (void)cs3;
    const unsigned int hv = *(const unsigned int*)(h_bf + (size_t)v * 128 + c2);
    const float zx = epsv * BFLO(hv) + ((acc0.x + acc1.x) + (acc2.x + acc3.x));
    const float zy = epsv * BFHI(hv) + ((acc0.y + acc1.y) + (acc2.y + acc3.y));
    const unsigned int zp = (unsigned int)f2bf(zx) | ((unsigned int)f2bf(zy) << 16);
    *(unsigned int*)(z_bf + (size_t)v * 128 + c2) = zp;
}

// ---------------- GEMM1: t = z @ W1, + BN1 partial stats ----------------
__global__ __launch_bounds__(256) void k_gemmB(
    const unsigned short* __restrict__ z_bf,
    const unsigned short* __restrict__ Wp,
    unsigned short* __restrict__ t_bf,
    float* __restrict__ ps, float* __restrict__ pq)
{
    __shared__ __align__(16) unsigned short zs[16 * 136];
    const int tid = threadIdx.x;
    const int r0 = blockIdx.x * 16;
    {
        const int row = tid & 15, c0 = (tid >> 4) * 8;
        *(bf16x8*)(&zs[row * 136 + c0]) =
            *(const bf16x8*)(z_bf + (size_t)(r0 + row) * 128 + c0);
    }
    __syncthreads();
    const int w = tid >> 6, l6 = tid & 63, m = l6 & 15, quad = l6 >> 4;
    const f32x4 z4 = {0.f, 0.f, 0.f, 0.f};
    f32x4 acc[4] = {z4, z4, z4, z4};
    const bf16x8* Wv = (const bf16x8*)Wp;
    #pragma unroll
    for (int kt = 0; kt < 4; ++kt) {
        const bf16x8 a = *(const bf16x8*)(&zs[m * 136 + kt * 32 + quad * 8]);
        #pragma unroll
        for (int f = 0; f < 4; ++f) {
            const bf16x8 b = Wv[((w * 4 + f) * 4 + kt) * 64 + l6];
            acc[f] = __builtin_amdgcn_mfma_f32_16x16x32_bf16(a, b, acc[f], 0, 0, 0);
        }
    }
    const int rowb = r0 + quad * 4;
    #pragma unroll
    for (int f = 0; f < 4; ++f) {
        const int col = w * 64 + f * 16 + m;
        float ssum = 0.f, ssq = 0.f;
        #pragma unroll
        for (int r = 0; r < 4; ++r) {
            const float val = acc[f][r];
            t_bf[(size_t)(rowb + r) * 256 + col] = f2bf(val);
            ssum += val; ssq += val * val;
        }
        ssum += __shfl_xor(ssum, 16); ssum += __shfl_xor(ssum, 32);
        ssq  += __shfl_xor(ssq , 16); ssq  += __shfl_xor(ssq , 32);
        if (quad == 0) {
            ps[(size_t)col * NPART + blockIdx.x] = ssum;
            pq[(size_t)col * NPART + blockIdx.x] = ssq;
        }
    }
}

// ---------------- BN stat fold: per-channel scale/shift ----------------
__global__ void k_bnstat(const float* __restrict__ ps, const float* __restrict__ pq,
                         const float* __restrict__ g, const float* __restrict__ beta,
                         float* __restrict__ sc, float* __restrict__ sh)
{
    const int c = blockIdx.x;
    const int tid = threadIdx.x;   // 256 threads
    const float* pr = ps + (size_t)c * NPART;
    const float* qr = pq + (size_t)c * NPART;
    float s = 0.f, q = 0.f;
    for (int i = tid; i < NPART; i += 256) { s += pr[i]; q += qr[i]; }
    #pragma unroll
    for (int off = 1; off < 64; off <<= 1) { s += __shfl_xor(s, off); q += __shfl_xor(q, off); }
    __shared__ float ls[4], lq[4];
    const int wv = tid >> 6;
    if ((tid & 63) == 0) { ls[wv] = s; lq[wv] = q; }
    __syncthreads();
    if (tid == 0) {
        const float S = ls[0] + ls[1] + ls[2] + ls[3];
        const float Q = lq[0] + lq[1] + lq[2] + lq[3];
        const float mean = S * (1.0f / NN);
        const float var  = Q * (1.0f / NN) - mean * mean;
        const float rs = rsqrtf(var + 1e-5f);
        const float scale = g[c] * rs;
        sc[c] = scale;
        sh[c] = beta[c] - mean * scale;
    }
}

// ---------------- GEMM2: v = relu(BN1(t)) @ W2 (bf16 out), + BN2 partial stats ----------------
__global__ __launch_bounds__(128) void k_gemmD(
    const unsigned short* __restrict__ t_bf,
    const float* __restrict__ sc1, const float* __restrict__ sh1,
    const unsigned short* __restrict__ Wp,
    unsigned short* __restrict__ vb,
    float* __restrict__ ps, float* __restrict__ pq)
{
    __shared__ __align__(16) unsigned short us[16 * 264];
    const int tid = threadIdx.x;
    const int r0 = blockIdx.x * 16;
    {
        const int row = tid & 15, g8 = (tid >> 4) * 8;
        #pragma unroll
        for (int cc = 0; cc < 4; ++cc) {
            const int c = cc * 64 + g8;
            union { bf16x8 v; unsigned short u[8]; } in, o;
            in.v = *(const bf16x8*)(t_bf + (size_t)(r0 + row) * 256 + c);
            const float4* scp = (const float4*)(sc1 + c);
            const float4* shp = (const float4*)(sh1 + c);
            const float4 s0 = scp[0], s1 = scp[1], b0 = shp[0], b1 = shp[1];
            float xv;
            xv = bf2f(in.u[0])*s0.x + b0.x; o.u[0] = f2bf(xv > 0.f ? xv : 0.f);
            xv = bf2f(in.u[1])*s0.y + b0.y; o.u[1] = f2bf(xv > 0.f ? xv : 0.f);
            xv = bf2f(in.u[2])*s0.z + b0.z; o.u[2] = f2bf(xv > 0.f ? xv : 0.f);
            xv = bf2f(in.u[3])*s0.w + b0.w; o.u[3] = f2bf(xv > 0.f ? xv : 0.f);
            xv = bf2f(in.u[4])*s1.x + b1.x; o.u[4] = f2bf(xv > 0.f ? xv : 0.f);
            xv = bf2f(in.u[5])*s1.y + b1.y; o.u[5] = f2bf(xv > 0.f ? xv : 0.f);
            xv = bf2f(in.u[6])*s1.z + b1.z; o.u[6] = f2bf(xv > 0.f ? xv : 0.f);
            xv = bf2f(in.u[7])*s1.w + b1.w; o.u[7] = f2bf(xv > 0.f ? xv : 0.f);
            *(bf16x8*)(&us[row * 264 + c]) = o.v;
        }
    }
    __syncthreads();
    const int w = tid >> 6, l6 = tid & 63, m = l6 & 15, quad = l6 >> 4;
    const f32x4 z4 = {0.f, 0.f, 0.f, 0.f};
    f32x4 acc[4] = {z4, z4, z4, z4};
    const bf16x8* Wv = (const bf16x8*)Wp;
    #pragma unroll
    for (int kt = 0; kt < 8; ++kt) {
        const bf16x8 a = *(const bf16x8*)(&us[m * 264 + kt * 32 + quad * 8]);
        #pragma unroll
        for (int f = 0; f < 4; ++f) {
            const bf16x8 b = Wv[((w * 4 + f) * 8 + kt) * 64 + l6];
            acc[f] = __builtin_amdgcn_mfma_f32_16x16x32_bf16(a, b, acc[f], 0, 0, 0);
        }
    }
    const int rowb = r0 + quad * 4;
    #pragma unroll
    for (int f = 0; f < 4; ++f) {
        const int col = w * 64 + f * 16 + m;
        float ssum = 0.f, ssq = 0.f;
        #pragma unroll
        for (int r = 0; r < 4; ++r) {
            const float val = acc[f][r];
            vb[(size_t)(rowb + r) * 128 + col] = f2bf(val);
            ssum += val; ssq += val * val;
        }
        ssum += __shfl_xor(ssum, 16); ssum += __shfl_xor(ssum, 32);
        ssq  += __shfl_xor(ssq , 16); ssq  += __shfl_xor(ssq , 32);
        if (quad == 0) {
            ps[(size_t)col * NPART + blockIdx.x] = ssum;
            pq[(size_t)col * NPART + blockIdx.x] = ssq;
        }
    }
}

// ---------------- BN2 + optional relu + residual (+ bf16 mirror), 8 ch/thread ----------------
__global__ void k_fin(const unsigned short* __restrict__ vb,
                      const float* __restrict__ sc2, const float* __restrict__ sh2,
                      float* __restrict__ h, unsigned short* __restrict__ h_bf,
                      const int do_relu)
{
    const int t = blockIdx.x * 256 + threadIdx.x;   // grid exactly N*128/8
    const int base = t * 8;
    const int c = base & 127;
    union { bf16x8 v; unsigned short u[8]; } in, ob;
    in.v = *(const bf16x8*)(vb + base);
    const float4 s0 = *(const float4*)(sc2 + c), s1 = *(const float4*)(sc2 + c + 4);
    const float4 b0 = *(const float4*)(sh2 + c), b1 = *(const float4*)(sh2 + c + 4);
    float4 h0 = *(const float4*)(h + base), h1 = *(const float4*)(h + base + 4);
    float z;
    z = bf2f(in.u[0])*s0.x + b0.x; if (do_relu) z = z > 0.f ? z : 0.f; h0.x += z;
    z = bf2f(in.u[1])*s0.y + b0.y; if (do_relu) z = z > 0.f ? z : 0.f; h0.y += z;
    z = bf2f(in.u[2])*s0.z + b0.z; if (do_relu) z = z > 0.f ? z : 0.f; h0.z += z;
    z = bf2f(in.u[3])*s0.w + b0.w; if (do_relu) z = z > 0.f ? z : 0.f; h0.w += z;
    z = bf2f(in.u[4])*s1.x + b1.x; if (do_relu) z = z > 0.f ? z : 0.f; h1.x += z;
    z = bf2f(in.u[5])*s1.y + b1.y; if (do_relu) z = z > 0.f ? z : 0.f; h1.y += z;
    z = bf2f(in.u[6])*s1.z + b1.z; if (do_relu) z = z > 0.f ? z : 0.f; h1.z += z;
    z = bf2f(in.u[7])*s1.w + b1.w; if (do_relu) z = z > 0.f ? z : 0.f; h1.w += z;
    *(float4*)(h + base) = h0;
    *(float4*)(h + base + 4) = h1;
    ob.u[0]=f2bf(h0.x); ob.u[1]=f2bf(h0.y); ob.u[2]=f2bf(h0.z); ob.u[3]=f2bf(h0.w);
    ob.u[4]=f2bf(h1.x); ob.u[5]=f2bf(h1.y); ob.u[6]=f2bf(h1.z); ob.u[7]=f2bf(h1.w);
    *(bf16x8*)(h_bf + base) = ob.v;
}

extern "C" void kernel_launch(void* const* d_in, const int* in_sizes, int n_in,
                              void* d_out, int out_size, void* d_ws, size_t ws_size,
                              hipStream_t stream)
{
    const float* x       = (const float*)d_in[0];
    const int*   ei      = (const int*)  d_in[1];
    const float* ea      = (const float*)d_in[2];
    const float* W_node  = (const float*)d_in[3];
    const float* b_node  = (const float*)d_in[4];
    const float* We      = (const float*)d_in[5];
    const float* be      = (const float*)d_in[6];
    const float* eps_gin = (const float*)d_in[7];
    const float* W1      = (const float*)d_in[8];
    // d_in[9] = b1: cancels exactly under BN1 (mean subtraction)
    const float* g1      = (const float*)d_in[10];
    const float* beta1   = (const float*)d_in[11];
    const float* W2      = (const float*)d_in[12];
    // d_in[13] = b2: cancels exactly under BN2
    const float* g_bn    = (const float*)d_in[14];
    const float* beta_bn = (const float*)d_in[15];

    float* h = (float*)d_out;

    char* W = (char*)d_ws;
    int*   counts   = (int*)  (W + 0);             // 200000 B (also fill cursor)
    int*   row_ptr  = (int*)  (W + 200000);        // 200004 B (pad to 400016)
    float* sc1      = (float*)(W + 400016);        // 1024 B
    float* sh1      = (float*)(W + 401040);        // 1024 B
    float* sc2      = (float*)(W + 402064);        // 512 B
    float* sh2      = (float*)(W + 402576);        // 512 B
    float* ps1      = (float*)(W + 403088);        // 3200000 B
    float* pq1      = (float*)(W + 3603088);       // 3200000 B
    float* ps2      = (float*)(W + 6803088);       // 1600000 B
    float* pq2      = (float*)(W + 8403088);       // 1600000 B
    int*   src_perm = (int*)  (W + 10003088);      // (EE+8)*4 = 3200032 B
    unsigned short* ea_bf = (unsigned short*)(W + 13203120); // (EE*16+128)*2 = 25600256 B
    unsigned short* Wp1   = (unsigned short*)(W + 38803376); // 327680 B
    unsigned short* Wp2   = (unsigned short*)(W + 39131056); // 327680 B
    unsigned short* z_bf  = (unsigned short*)(W + 39458736); // 12800000 B (also vb alias)
    unsigned short* t_bf  = (unsigned short*)(W + 52258736); // 25600000 B
    unsigned short* h_bf  = (unsigned short*)(W + 77858736); // 12800000 B -> total ~90.7 MB
    unsigned short* vb    = z_bf;  // safe alias: z_bf dead after gemmB, vb born in gemmD

    (void)hipMemsetAsync(counts, 0, 200000, stream);
    (void)hipMemsetAsync(src_perm + EE, 0, 32, stream);   // pipeline overrun pad

    k_node_enc<<<dim3(NN * DD / 256), dim3(256), 0, stream>>>(x, W_node, b_node, h, h_bf);
    k_count<<<dim3(EE / 256), dim3(256), 0, stream>>>(ei, counts);
    k_scan<<<dim3(1), dim3(1024), 0, stream>>>(counts, row_ptr);
    k_fill<<<dim3(EE / 256), dim3(256), 0, stream>>>(ei, ea, counts, src_perm, ea_bf);
    k_pack<<<dim3(2 * LL * 32768 / 256), dim3(256), 0, stream>>>(W1, W2, Wp1, Wp2);

    for (int l = 0; l < LL; ++l) {
        k_agg<<<dim3(NN / 4), dim3(256), 0, stream>>>(
            h_bf, ea_bf, We + (size_t)l * FF * DD, be + (size_t)l * DD,
            eps_gin, l, row_ptr, src_perm, z_bf);
        k_gemmB<<<dim3(NPART), dim3(256), 0, stream>>>(
            z_bf, Wp1 + (size_t)l * 32768, t_bf, ps1, pq1);
        k_bnstat<<<dim3(256), dim3(256), 0, stream>>>(
            ps1, pq1, g1 + (size_t)l * 256, beta1 + (size_t)l * 256, sc1, sh1);
        k_gemmD<<<dim3(NPART), dim3(128), 0, stream>>>(
            t_bf, sc1, sh1, Wp2 + (size_t)l * 32768, vb, ps2, pq2);
        k_bnstat<<<dim3(128), dim3(256), 0, stream>>>(
            ps2, pq2, g_bn + (size_t)l * 128, beta_bn + (size_t)l * 128, sc2, sh2);
        k_fin<<<dim3(NN * DD / 8 / 256), dim3(256), 0, stream>>>(
            vb, sc2, sh2, h, h_bf, (l < LL - 1) ? 1 : 0);
    }
}